// Round 1
// baseline (613.035 us; speedup 1.0000x reference)
//
#include <hip/hip_runtime.h>

// MoE top-2 of 3x3 SAME convs, fp32 direct conv baseline.
// x: [B,C,H,W] f32, gate_w: [B,K] f32, gate_i: [B,K] i32,
// Wexp: [E,CO,C,3,3] f32, bexp: [E,CO] f32, out: [B,CO,H,W] f32.
// out[b,co] = g0*relu(conv(x[b], Wexp[e0,co]) + bexp[e0,co])
//           + g1*relu(conv(x[b], Wexp[e1,co]) + bexp[e1,co])

#define BB 64
#define CC 64
#define COO 64
#define HH 56
#define WW 56
#define EE 8
#define KK 2

// Per-thread tile: 4 consecutive w pixels x 4 co x 2 expert slots = 32 accum.
// Block: 256 threads over pixel-groups (14 w-groups * 56 rows = 784 groups).
__global__ __launch_bounds__(256) void moe_conv3x3_direct(
    const float* __restrict__ x,
    const float* __restrict__ gate_w,
    const int*   __restrict__ gate_i,
    const float* __restrict__ Wexp,
    const float* __restrict__ bexp,
    float* __restrict__ out)
{
    const int b       = blockIdx.z;
    const int co_base = blockIdx.y * 4;
    const int pg      = blockIdx.x * 256 + threadIdx.x;
    const int NPG     = (WW / 4) * HH;   // 14 * 56 = 784
    if (pg >= NPG) return;

    const int h  = pg / (WW / 4);
    const int w0 = (pg % (WW / 4)) * 4;  // 16B-aligned column base

    const int   e0 = gate_i[b * KK + 0];
    const int   e1 = gate_i[b * KK + 1];
    const float g0 = gate_w[b * KK + 0];
    const float g1 = gate_w[b * KK + 1];

    const float* wbase0 = Wexp + ((size_t)e0 * COO + co_base) * (CC * 9);
    const float* wbase1 = Wexp + ((size_t)e1 * COO + co_base) * (CC * 9);
    const float* xb     = x + (size_t)b * CC * HH * WW;

    float acc0[4][4];  // [co][px]
    float acc1[4][4];
    #pragma unroll
    for (int i = 0; i < 4; ++i)
        #pragma unroll
        for (int j = 0; j < 4; ++j) { acc0[i][j] = 0.f; acc1[i][j] = 0.f; }

    #pragma unroll 1
    for (int c = 0; c < CC; ++c) {
        const float* xc = xb + c * HH * WW;
        #pragma unroll
        for (int r = 0; r < 3; ++r) {
            const int hr = h + r - 1;
            if (hr < 0 || hr >= HH) continue;   // zero-pad row: skip taps
            const float* xrow = xc + hr * WW;

            // 6-wide input window covering 4 px x 3 s-taps
            float wv[6];
            const float4 xm = *(const float4*)(xrow + w0);   // aligned
            wv[0] = (w0 > 0)       ? xrow[w0 - 1] : 0.f;     // left pad
            wv[1] = xm.x; wv[2] = xm.y; wv[3] = xm.z; wv[4] = xm.w;
            wv[5] = (w0 + 4 < WW)  ? xrow[w0 + 4] : 0.f;     // right pad

            #pragma unroll
            for (int i = 0; i < 4; ++i) {
                const float* wp0 = wbase0 + (size_t)i * CC * 9 + c * 9 + r * 3;
                const float* wp1 = wbase1 + (size_t)i * CC * 9 + c * 9 + r * 3;
                #pragma unroll
                for (int s = 0; s < 3; ++s) {
                    const float f0 = wp0[s];   // wave-uniform -> scalar pipe
                    const float f1 = wp1[s];
                    #pragma unroll
                    for (int j = 0; j < 4; ++j) {
                        const float xv = wv[j + s];
                        acc0[i][j] = fmaf(f0, xv, acc0[i][j]);
                        acc1[i][j] = fmaf(f1, xv, acc1[i][j]);
                    }
                }
            }
        }
    }

    // Epilogue: bias + relu + gated combine, 16B stores
    #pragma unroll
    for (int i = 0; i < 4; ++i) {
        const int co = co_base + i;
        const float bias0 = bexp[e0 * COO + co];
        const float bias1 = bexp[e1 * COO + co];
        float v[4];
        #pragma unroll
        for (int j = 0; j < 4; ++j) {
            float a0 = acc0[i][j] + bias0; a0 = a0 > 0.f ? a0 : 0.f;
            float a1 = acc1[i][j] + bias1; a1 = a1 > 0.f ? a1 : 0.f;
            v[j] = g0 * a0 + g1 * a1;
        }
        float4 o; o.x = v[0]; o.y = v[1]; o.z = v[2]; o.w = v[3];
        *(float4*)(out + (((size_t)b * COO + co) * HH + h) * WW + w0) = o;
    }
}

extern "C" void kernel_launch(void* const* d_in, const int* in_sizes, int n_in,
                              void* d_out, int out_size, void* d_ws, size_t ws_size,
                              hipStream_t stream) {
    const float* x      = (const float*)d_in[0];
    const float* gate_w = (const float*)d_in[1];
    const int*   gate_i = (const int*)  d_in[2];
    const float* Wexp   = (const float*)d_in[3];
    const float* bexp   = (const float*)d_in[4];
    float* out = (float*)d_out;

    // pg tiles: ceil(784/256)=4 ; co tiles: 64/4=16 ; samples: 64
    dim3 grid(4, 16, BB);
    moe_conv3x3_direct<<<grid, 256, 0, stream>>>(x, gate_w, gate_i, Wexp, bexp, out);
}

// Round 3
// 173.580 us; speedup vs baseline: 3.5317x; 3.5317x over previous
//
#include <hip/hip_runtime.h>

// MoE top-2 of 3x3 SAME convs via bf16 MFMA implicit GEMM.
//
// R3 fix: R2 placed Wpack at ws offset 31,334,400 but xT actually needs
// 31,358,976 B (64*58*66*64 bf16) -> Wpack clobbered the tail of b=63's
// xT (absmax 3.43, localized). Now Wpack sits at offset 0 (fixed 589,824 B)
// and xT after it; no overlap possible.
//
// Decomposition: conv3x3 = sum over 9 taps (r,s) of rank-C GEMMs:
//   Y[co, (h,w)] += W[e][co][c][r][s] * x[c][h+r-1][w+s-1]
// P0: x [B,C,H,W] f32 -> xT [B][58][66][C] bf16, zero-padded rows/cols.
// P1: Wexp f32 -> Wpack bf16, MFMA A-frag-linear [e][r][s][ks][mt][lane][j].
// Main: block = 4 waves = 64co x 64w x 2rows per (b, row-pair); weights for
// both slots of one r staged in LDS (48 KB); B-frags from L2-resident xT.

#define BB 64
#define CC 64
#define COO 64
#define HH 56
#define WW 56

typedef __bf16 bf16x8 __attribute__((ext_vector_type(8)));
typedef float  f32x4  __attribute__((ext_vector_type(4)));

// ---- P0: transpose + bf16 convert + zero-pad -------------------------------
__global__ __launch_bounds__(256) void xpose_kernel(
    const float* __restrict__ x, __bf16* __restrict__ xT)
{
    const int b  = blockIdx.y;
    const int hp = blockIdx.x;          // 0..57
    const int tid = threadIdx.x;
    __shared__ float tile[CC][WW + 1];  // +1: bank-conflict pad

    const bool interior = (hp >= 1 && hp <= HH);
    if (interior) {
        const int h = hp - 1;
        for (int i = tid; i < CC * WW; i += 256) {
            const int c = i / WW, w = i % WW;
            tile[c][w] = x[(((size_t)b * CC + c) * HH + h) * WW + w];
        }
    }
    __syncthreads();
    __bf16* dst = xT + ((size_t)b * 58 + hp) * 66 * CC;
    for (int j = tid; j < 66 * CC; j += 256) {
        const int wc = j >> 6, c = j & 63;
        float v = 0.f;
        if (interior && wc >= 1 && wc <= WW) v = tile[c][wc - 1];
        dst[j] = (__bf16)v;
    }
}

// ---- P1: weight pack into A-frag-linear layout -----------------------------
// Wpack[e*36864 + (r*3+s)*4096 + ks*2048 + mt*512 + lane*8 + j]
//   = bf16( Wexp[e][mt*16 + (lane&15)][ks*32 + (lane>>4)*8 + j][r][s] )
__global__ __launch_bounds__(256) void wpack_kernel(
    const float* __restrict__ Wexp, __bf16* __restrict__ Wpack)
{
    const int rs = blockIdx.x;          // 0..8  (r*3+s)
    const int e  = blockIdx.y;          // 0..7
    const int r = rs / 3, s = rs % 3;
    for (int idx = threadIdx.x; idx < 4096; idx += 256) {
        const int ks   = idx >> 11;
        const int rem  = idx & 2047;
        const int mt   = rem >> 9;
        const int lane = (rem >> 3) & 63;
        const int j    = idx & 7;
        const int co = mt * 16 + (lane & 15);
        const int c  = ks * 32 + ((lane >> 4) << 3) + j;
        const float v = Wexp[((((size_t)e * COO + co) * CC + c) * 3 + r) * 3 + s];
        Wpack[(size_t)e * 36864 + (size_t)rs * 4096 + idx] = (__bf16)v;
    }
}

// ---- Main: MFMA implicit GEMM ----------------------------------------------
__global__ __launch_bounds__(256, 3) void moe_conv_mfma(
    const __bf16* __restrict__ xT, const __bf16* __restrict__ Wpack,
    const float* __restrict__ gate_w, const int* __restrict__ gate_i,
    const float* __restrict__ bexp, float* __restrict__ out)
{
    __shared__ __bf16 ldsA[2 * 12288];  // [slot][s][ks][mt][lane][j] = 48 KB

    const int b   = blockIdx.y;
    const int h0  = blockIdx.x * 2;     // rows h0, h0+1
    const int tid = threadIdx.x;
    const int wid = tid >> 6, lane = tid & 63;
    const int n15 = lane & 15, quad = lane >> 4;
    const int wcol = wid * 16 + n15;    // padded col 0..63

    const int   e0 = gate_i[b * 2 + 0], e1 = gate_i[b * 2 + 1];
    const float g0 = gate_w[b * 2 + 0], g1 = gate_w[b * 2 + 1];

    const __bf16* xb = xT + (size_t)b * 58 * 66 * CC;

    f32x4 acc[2][4][2] = {};            // [slot][mt][row]

    for (int r = 0; r < 3; ++r) {
        __syncthreads();                // prior r's LDS readers done
        {   // stage both slots' (r, all s) A-frags: 48 chunks of 1 KB
            const __bf16* s0 = Wpack + (size_t)e0 * 36864 + r * 12288;
            const __bf16* s1 = Wpack + (size_t)e1 * 36864 + r * 12288;
            #pragma unroll
            for (int i = 0; i < 12; ++i) {
                const int q    = wid * 12 + i;       // 0..47
                const int slot = q >= 24;
                const int rem  = q - slot * 24;
                const __bf16* src = (slot ? s1 : s0) + rem * 512 + lane * 8;
                const uint4 tmp = *(const uint4*)src;
                *(uint4*)&ldsA[q * 512 + lane * 8] = tmp;
            }
        }
        __syncthreads();

        #pragma unroll
        for (int s = 0; s < 3; ++s) {
            #pragma unroll
            for (int ks = 0; ks < 2; ++ks) {
                bf16x8 bf[2];
                #pragma unroll
                for (int t = 0; t < 2; ++t) {
                    const int hr1 = h0 + t + r;      // padded row 0..57
                    const int wc1 = wcol + s;        // padded col 0..65
                    bf[t] = *(const bf16x8*)(
                        xb + (size_t)(hr1 * 66 + wc1) * CC + ks * 32 + quad * 8);
                }
                #pragma unroll
                for (int slot = 0; slot < 2; ++slot) {
                    #pragma unroll
                    for (int mt = 0; mt < 4; ++mt) {
                        const bf16x8 af = *(const bf16x8*)
                            &ldsA[slot * 12288 + (s * 2 + ks) * 2048 + mt * 512 + lane * 8];
                        #pragma unroll
                        for (int t = 0; t < 2; ++t)
                            acc[slot][mt][t] = __builtin_amdgcn_mfma_f32_16x16x32_bf16(
                                af, bf[t], acc[slot][mt][t], 0, 0, 0);
                    }
                }
            }
        }
    }

    // Epilogue: D layout col=lane&15 (pixel), row=quad*4+reg (co within mt)
    if (wcol < WW) {
        #pragma unroll
        for (int t = 0; t < 2; ++t) {
            const int h = h0 + t;
            #pragma unroll
            for (int mt = 0; mt < 4; ++mt) {
                #pragma unroll
                for (int v = 0; v < 4; ++v) {
                    const int co = mt * 16 + quad * 4 + v;
                    float a0 = acc[0][mt][t][v] + bexp[e0 * COO + co];
                    float a1 = acc[1][mt][t][v] + bexp[e1 * COO + co];
                    a0 = fmaxf(a0, 0.f);
                    a1 = fmaxf(a1, 0.f);
                    out[(((size_t)b * COO + co) * HH + h) * WW + wcol] =
                        g0 * a0 + g1 * a1;
                }
            }
        }
    }
}

extern "C" void kernel_launch(void* const* d_in, const int* in_sizes, int n_in,
                              void* d_out, int out_size, void* d_ws, size_t ws_size,
                              hipStream_t stream) {
    const float* x      = (const float*)d_in[0];
    const float* gate_w = (const float*)d_in[1];
    const int*   gate_i = (const int*)  d_in[2];
    const float* Wexp   = (const float*)d_in[3];
    const float* bexp   = (const float*)d_in[4];
    float* out = (float*)d_out;

    // Wpack first (fixed 589,824 B, 16B-aligned), then xT (31,358,976 B).
    __bf16* Wpack = (__bf16*)d_ws;
    __bf16* xT    = (__bf16*)((char*)d_ws + 589824);

    xpose_kernel<<<dim3(58, BB), 256, 0, stream>>>(x, xT);
    wpack_kernel<<<dim3(9, 8),  256, 0, stream>>>(Wexp, Wpack);
    moe_conv_mfma<<<dim3(28, BB), 256, 0, stream>>>(xT, Wpack, gate_w, gate_i,
                                                    bexp, out);
}

// Round 4
// 163.529 us; speedup vs baseline: 3.7488x; 1.0615x over previous
//
#include <hip/hip_runtime.h>

// MoE top-2 of 3x3 SAME convs via bf16 MFMA implicit GEMM.
//
// R4: (a) main kernel processes 4 rows per block (was 2): each A-frag LDS
// read now feeds 4 MFMAs -> 256 B/MFMA vs the ~343 B/MFMA LDS budget at
// full MFMA rate (was 512 -> LDS pipe 1.5x oversubscribed, MfmaUtil 21%).
// (b) xpose rewritten with float4 staging + coalesced bf16x8 stores (was
// 2 B scalar stores).
//
// P0: x [B,C,H,W] f32 -> xT [B][58][66][C] bf16, zero-padded rows/cols.
// P1: Wexp f32 -> Wpack bf16, MFMA A-frag-linear [e][r][s][ks][mt][lane][j].
// Main: block = 4 waves = 64co x 64px x 4rows per (b, row-quad); weights for
// both slots of one r staged in LDS (48 KB); B-frags from L2-resident xT.

#define BB 64
#define CC 64
#define COO 64
#define HH 56
#define WW 56

typedef __bf16 bf16x8 __attribute__((ext_vector_type(8)));
typedef float  f32x4  __attribute__((ext_vector_type(4)));

// ---- P0: transpose + bf16 convert + zero-pad -------------------------------
// xT[b][hp][wc][c]; hp=h+1 in [0,58), wc=w+1 in [0,66); pads are zero.
__global__ __launch_bounds__(256) void xpose_kernel(
    const float* __restrict__ x, __bf16* __restrict__ xT)
{
    const int b   = blockIdx.y;
    const int hp  = blockIdx.x;          // 0..57
    const int tid = threadIdx.x;
    __shared__ float tile[CC][WW + 1];   // stride 57: 2-way max bank alias

    __bf16* dst = xT + ((size_t)b * 58 + hp) * 66 * CC;
    const bool interior = (hp >= 1 && hp <= HH);

    if (!interior) {                     // top/bottom pad row: zero-fill
        bf16x8 z = {};
        for (int j = tid; j < 66 * CC / 8; j += 256)
            *(bf16x8*)(dst + j * 8) = z;
        return;
    }

    const int h = hp - 1;
    const float* xb = x + (size_t)b * CC * HH * WW + (size_t)h * WW;
    // stage: 64 c-rows x 14 float4
    for (int i = tid; i < CC * 14; i += 256) {
        const int c = i / 14, wq = i % 14;
        const float4 f = *(const float4*)(xb + (size_t)c * HH * WW + wq * 4);
        tile[c][wq * 4 + 0] = f.x; tile[c][wq * 4 + 1] = f.y;
        tile[c][wq * 4 + 2] = f.z; tile[c][wq * 4 + 3] = f.w;
    }
    __syncthreads();
    // emit: 66 wc x 8 c-groups, 16 B coalesced stores
    for (int j = tid; j < 66 * 8; j += 256) {
        const int wc = j >> 3, cg = j & 7;
        bf16x8 v = {};
        if (wc >= 1 && wc <= WW) {
            const int w = wc - 1;
            #pragma unroll
            for (int u = 0; u < 8; ++u) v[u] = (__bf16)tile[cg * 8 + u][w];
        }
        *(bf16x8*)(dst + wc * CC + cg * 8) = v;
    }
}

// ---- P1: weight pack into A-frag-linear layout -----------------------------
// Wpack[e*36864 + (r*3+s)*4096 + ks*2048 + mt*512 + lane*8 + j]
//   = bf16( Wexp[e][mt*16 + (lane&15)][ks*32 + (lane>>4)*8 + j][r][s] )
__global__ __launch_bounds__(256) void wpack_kernel(
    const float* __restrict__ Wexp, __bf16* __restrict__ Wpack)
{
    const int rs = blockIdx.x;          // 0..8  (r*3+s)
    const int e  = blockIdx.y;          // 0..7
    const int r = rs / 3, s = rs % 3;
    for (int idx = threadIdx.x; idx < 4096; idx += 256) {
        const int ks   = idx >> 11;
        const int rem  = idx & 2047;
        const int mt   = rem >> 9;
        const int lane = (rem >> 3) & 63;
        const int j    = idx & 7;
        const int co = mt * 16 + (lane & 15);
        const int c  = ks * 32 + ((lane >> 4) << 3) + j;
        const float v = Wexp[((((size_t)e * COO + co) * CC + c) * 3 + r) * 3 + s];
        Wpack[(size_t)e * 36864 + (size_t)rs * 4096 + idx] = (__bf16)v;
    }
}

// ---- Main: MFMA implicit GEMM, 4 rows/block --------------------------------
__global__ __launch_bounds__(256, 2) void moe_conv_mfma(
    const __bf16* __restrict__ xT, const __bf16* __restrict__ Wpack,
    const float* __restrict__ gate_w, const int* __restrict__ gate_i,
    const float* __restrict__ bexp, float* __restrict__ out)
{
    __shared__ __bf16 ldsA[2 * 12288];  // [slot][s][ks][mt][lane][j] = 48 KB

    const int b   = blockIdx.y;
    const int h0  = blockIdx.x * 4;     // rows h0..h0+3
    const int tid = threadIdx.x;
    const int wid = tid >> 6, lane = tid & 63;
    const int n15 = lane & 15, quad = lane >> 4;
    const int wcol = wid * 16 + n15;    // padded col 0..63

    const int   e0 = gate_i[b * 2 + 0], e1 = gate_i[b * 2 + 1];
    const float g0 = gate_w[b * 2 + 0], g1 = gate_w[b * 2 + 1];

    const __bf16* xb = xT + (size_t)b * 58 * 66 * CC;

    f32x4 acc[2][4][4] = {};            // [slot][mt][row t]

    for (int r = 0; r < 3; ++r) {
        __syncthreads();                // prior r's LDS readers done
        {   // stage both slots' (r, all s) A-frags: 48 chunks of 1 KB
            const __bf16* s0 = Wpack + (size_t)e0 * 36864 + r * 12288;
            const __bf16* s1 = Wpack + (size_t)e1 * 36864 + r * 12288;
            #pragma unroll
            for (int i = 0; i < 12; ++i) {
                const int q    = wid * 12 + i;       // 0..47
                const int slot = q >= 24;
                const int rem  = q - slot * 24;
                const __bf16* src = (slot ? s1 : s0) + rem * 512 + lane * 8;
                const uint4 tmp = *(const uint4*)src;
                *(uint4*)&ldsA[q * 512 + lane * 8] = tmp;
            }
        }
        __syncthreads();

        #pragma unroll
        for (int s = 0; s < 3; ++s) {
            #pragma unroll
            for (int ks = 0; ks < 2; ++ks) {
                bf16x8 bf[4];
                #pragma unroll
                for (int t = 0; t < 4; ++t) {
                    const int hr1 = h0 + t + r;      // padded row 0..57
                    const int wc1 = wcol + s;        // padded col 0..65
                    bf[t] = *(const bf16x8*)(
                        xb + (size_t)(hr1 * 66 + wc1) * CC + ks * 32 + quad * 8);
                }
                #pragma unroll
                for (int slot = 0; slot < 2; ++slot) {
                    #pragma unroll
                    for (int mt = 0; mt < 4; ++mt) {
                        const bf16x8 af = *(const bf16x8*)
                            &ldsA[slot * 12288 + (s * 2 + ks) * 2048 + mt * 512 + lane * 8];
                        #pragma unroll
                        for (int t = 0; t < 4; ++t)
                            acc[slot][mt][t] = __builtin_amdgcn_mfma_f32_16x16x32_bf16(
                                af, bf[t], acc[slot][mt][t], 0, 0, 0);
                    }
                }
            }
        }
    }

    // Epilogue: D layout col=lane&15 (pixel), row=quad*4+reg (co within mt)
    if (wcol < WW) {
        #pragma unroll
        for (int t = 0; t < 4; ++t) {
            const int h = h0 + t;
            #pragma unroll
            for (int mt = 0; mt < 4; ++mt) {
                #pragma unroll
                for (int v = 0; v < 4; ++v) {
                    const int co = mt * 16 + quad * 4 + v;
                    float a0 = acc[0][mt][t][v] + bexp[e0 * COO + co];
                    float a1 = acc[1][mt][t][v] + bexp[e1 * COO + co];
                    a0 = fmaxf(a0, 0.f);
                    a1 = fmaxf(a1, 0.f);
                    out[(((size_t)b * COO + co) * HH + h) * WW + wcol] =
                        g0 * a0 + g1 * a1;
                }
            }
        }
    }
}

extern "C" void kernel_launch(void* const* d_in, const int* in_sizes, int n_in,
                              void* d_out, int out_size, void* d_ws, size_t ws_size,
                              hipStream_t stream) {
    const float* x      = (const float*)d_in[0];
    const float* gate_w = (const float*)d_in[1];
    const int*   gate_i = (const int*)  d_in[2];
    const float* Wexp   = (const float*)d_in[3];
    const float* bexp   = (const float*)d_in[4];
    float* out = (float*)d_out;

    // Wpack first (fixed 589,824 B, 16B-aligned), then xT (31,358,976 B).
    __bf16* Wpack = (__bf16*)d_ws;
    __bf16* xT    = (__bf16*)((char*)d_ws + 589824);

    xpose_kernel<<<dim3(58, BB), 256, 0, stream>>>(x, xT);
    wpack_kernel<<<dim3(9, 8),  256, 0, stream>>>(Wexp, Wpack);
    moe_conv_mfma<<<dim3(14, BB), 256, 0, stream>>>(xT, Wpack, gate_w, gate_i,
                                                    bexp, out);
}